// Round 4
// baseline (741.449 us; speedup 1.0000x reference)
//
#include <hip/hip_runtime.h>

typedef __attribute__((ext_vector_type(8))) short bf16x8;
typedef __attribute__((ext_vector_type(4))) float f32x4;

constexpr int EMBED = 64;
constexpr int RBF   = 16;
constexpr int EPB   = 256;   // edges per block (4 waves x 64)
constexpr int EPW   = 64;    // edges per wave

__device__ __forceinline__ short f2bf(float f) {
    unsigned u = __float_as_uint(f);
    unsigned r = (u + 0x7fffu + ((u >> 16) & 1u)) >> 16;   // RNE
    return (short)(r & 0xffffu);
}

// ---------------------------------------------------------------------------
// Edge kernel, MFMA + software-pipelined.
//   Hoist: all 4 M-tiles' A1 fragments built up front (overlapped load latency)
//   Pass A: 4x (GEMM1 + SiLU + swizzled LDS write) into per-tile regions, no
//           intra-pass barriers -> full ILP across tiles
//   fence
//   Pass B: 4x (swizzled LDS read + GEMM2 + coalesced atomics) -> atomics of
//           tile t overlap MFMAs of tile t+1
// ---------------------------------------------------------------------------
__global__ __launch_bounds__(256, 2) void edge_kernel(
    const float* __restrict__ coord,
    const float* __restrict__ rbf,
    const int* __restrict__ edge_index,
    const float* __restrict__ W1,
    const float* __restrict__ b1,
    const float* __restrict__ W2,
    const float* __restrict__ b2,
    float* __restrict__ agg,
    long long E)
{
    __shared__ int lds_row[EPB];
    __shared__ __align__(16) short lds_s[4][4][16 * 64];  // [wave][mtile][16e x 64ch]

    const int tid  = threadIdx.x;
    const int lane = tid & 63;
    const int wave = tid >> 6;
    const int g = lane >> 4;     // 16-lane group 0..3
    const int c = lane & 15;
    const long long blk_e0 = (long long)blockIdx.x * EPB;

    // lds_row is written and read wave-locally -> wave fence suffices
    {
        long long e = blk_e0 + tid;
        lds_row[tid] = (e < E) ? edge_index[e] : 0;
    }
    __builtin_amdgcn_wave_barrier();

    // ---- B fragments (VGPR-resident). B layout: n = c, k = g*8 + j ----
    bf16x8 b1f[4];
#pragma unroll
    for (int t = 0; t < 4; ++t) {
#pragma unroll
        for (int j = 0; j < 8; ++j) {
            const int k = g * 8 + j;
            const int n = t * 16 + c;
            b1f[t][j] = (k <= RBF) ? f2bf(W1[k * EMBED + n]) : (short)0;
        }
    }
    bf16x8 b2f[2][4];
#pragma unroll
    for (int kk = 0; kk < 2; ++kk)
#pragma unroll
        for (int t = 0; t < 4; ++t)
#pragma unroll
            for (int j = 0; j < 8; ++j) {
                const int k = kk * 32 + g * 8 + j;
                const int n = t * 16 + c;
                b2f[kk][t][j] = f2bf(W2[k * EMBED + n]);
            }
    float b1v[4], b2v[4];
#pragma unroll
    for (int t = 0; t < 4; ++t) {
        b1v[t] = b1[t * 16 + c];
        b2v[t] = b2[t * 16 + c];
    }

    const long long wave_e0 = blk_e0 + (long long)wave * EPW;

    // ================= hoisted A1 builds (loads overlap) =================
    bf16x8 a1[4];
#pragma unroll
    for (int mt = 0; mt < 4; ++mt) {
        bf16x8 a = {};
        const long long e0 = wave_e0 + mt * 16;
        const int eloc0 = wave * EPW + mt * 16;
        const long long ea = e0 + c;
        const bool ev = (ea < E);
        if (g < 2) {
            if (ev) {
                const float4 p0 = *reinterpret_cast<const float4*>(rbf + ea * RBF + g * 8);
                const float4 p1 = *reinterpret_cast<const float4*>(rbf + ea * RBF + g * 8 + 4);
                a[0] = f2bf(p0.x); a[1] = f2bf(p0.y); a[2] = f2bf(p0.z); a[3] = f2bf(p0.w);
                a[4] = f2bf(p1.x); a[5] = f2bf(p1.y); a[6] = f2bf(p1.z); a[7] = f2bf(p1.w);
            }
        } else if (g == 2) {
            if (ev) {  // k=16 = angle, faithful to reference
                const int row = lds_row[eloc0 + c];
                const int col = edge_index[E + ea];
                const float vx = coord[row * 3 + 0] - coord[col * 3 + 0];
                const float vy = coord[row * 3 + 1] - coord[col * 3 + 1];
                const float vz = coord[row * 3 + 2] - coord[col * 3 + 2];
                const float sq = vx * vx + vy * vy + vz * vz;
                const float nrm = fmaxf(sqrtf(sq), 1e-12f);
                const float inv = 1.0f / nrm;
                const float ux = vx * inv, uy = vy * inv, uz = vz * inv;
                const float s2 = ux * ux + uy * uy + uz * uz;
                const float cosang = fminf(fmaxf(-s2, -1.0f), 1.0f);
                const float ang = acosf(cosang);
                a[0] = f2bf(ang);
            }
        }
        a1[mt] = a;
    }

    // ================= pass A: GEMM1 + SiLU + LDS (per-tile regions) =====
#pragma unroll
    for (int mt = 0; mt < 4; ++mt) {
        f32x4 acc1[4];
#pragma unroll
        for (int t = 0; t < 4; ++t) {
            f32x4 ci = {b1v[t], b1v[t], b1v[t], b1v[t]};
            acc1[t] = __builtin_amdgcn_mfma_f32_16x16x32_bf16(a1[mt], b1f[t], ci, 0, 0, 0);
        }
        char* const sl = reinterpret_cast<char*>(lds_s[wave][mt]);
#pragma unroll
        for (int t = 0; t < 4; ++t)
#pragma unroll
            for (int r = 0; r < 4; ++r) {
                const float x = acc1[t][r];
                const float s = x / (1.0f + __expf(-x));
                const int erow = g * 4 + r;
                const int byte = erow * 128 + ((t * 32 + 2 * c) ^ ((erow & 7) << 4));
                *reinterpret_cast<short*>(sl + byte) = f2bf(s);
            }
    }
    __builtin_amdgcn_wave_barrier();

    // ================= pass B: GEMM2 + atomics ===========================
#pragma unroll
    for (int mt = 0; mt < 4; ++mt) {
        const long long e0 = wave_e0 + mt * 16;
        const int eloc0 = wave * EPW + mt * 16;
        const char* const sl = reinterpret_cast<const char*>(lds_s[wave][mt]);

        bf16x8 a2[2];
#pragma unroll
        for (int kk = 0; kk < 2; ++kk) {
            const int byte = c * 128 + ((kk * 64 + g * 16) ^ ((c & 7) << 4));
            a2[kk] = *reinterpret_cast<const bf16x8*>(sl + byte);
        }

        f32x4 acc2[4];
#pragma unroll
        for (int t = 0; t < 4; ++t) {
            f32x4 ci = {b2v[t], b2v[t], b2v[t], b2v[t]};
            acc2[t] = __builtin_amdgcn_mfma_f32_16x16x32_bf16(a2[0], b2f[0][t], ci, 0, 0, 0);
            acc2[t] = __builtin_amdgcn_mfma_f32_16x16x32_bf16(a2[1], b2f[1][t], acc2[t], 0, 0, 0);
        }

        // lane holds edge g*4+r, chan t*16+c
#pragma unroll
        for (int r = 0; r < 4; ++r) {
            const long long eat = e0 + g * 4 + r;
            if (eat < E) {
                float* const dst = agg + (long long)lds_row[eloc0 + g * 4 + r] * EMBED;
#pragma unroll
                for (int t = 0; t < 4; ++t)
                    atomicAdd(dst + t * 16 + c, acc2[t][r]);
            }
        }
    }
}

// ---------------------------------------------------------------------------
// Node kernel: out = x + W4 @ silu(W3 @ agg + b3) + b4 ; one wave per node.
// No min-wave bound: let the 128-float weight arrays live in VGPRs.
// ---------------------------------------------------------------------------
__global__ __launch_bounds__(256) void node_kernel(
    const float* __restrict__ x,
    const float* __restrict__ agg,
    const float* __restrict__ W3,
    const float* __restrict__ b3,
    const float* __restrict__ W4,
    const float* __restrict__ b4,
    float* __restrict__ out,
    int nn)
{
    __shared__ __align__(16) float lds_s[4][EMBED];
    const int lane = threadIdx.x & 63;
    const int wave = threadIdx.x >> 6;

    float w3c[EMBED], w4c[EMBED];
#pragma unroll
    for (int j = 0; j < EMBED; ++j) w3c[j] = W3[j * EMBED + lane];
#pragma unroll
    for (int j = 0; j < EMBED; ++j) w4c[j] = W4[j * EMBED + lane];
    const float b3v = b3[lane];
    const float b4v = b4[lane];

    const float4* s4 = reinterpret_cast<const float4*>(lds_s[wave]);

    const int wid = blockIdx.x * 4 + wave;
    const int nw  = gridDim.x * 4;
    for (int n = wid; n < nn; n += nw) {
        const long long base = (long long)n * EMBED + lane;
        const float a = agg[base];

        lds_s[wave][lane] = a;
        __builtin_amdgcn_wave_barrier();

        float acc = b3v;
#pragma unroll
        for (int j4 = 0; j4 < EMBED / 4; ++j4) {
            const float4 sv = s4[j4];
            acc = fmaf(sv.x, w3c[4 * j4 + 0], acc);
            acc = fmaf(sv.y, w3c[4 * j4 + 1], acc);
            acc = fmaf(sv.z, w3c[4 * j4 + 2], acc);
            acc = fmaf(sv.w, w3c[4 * j4 + 3], acc);
        }
        const float s = acc / (1.0f + __expf(-acc));

        __builtin_amdgcn_wave_barrier();
        lds_s[wave][lane] = s;
        __builtin_amdgcn_wave_barrier();

        float acc2 = b4v;
#pragma unroll
        for (int j4 = 0; j4 < EMBED / 4; ++j4) {
            const float4 sv = s4[j4];
            acc2 = fmaf(sv.x, w4c[4 * j4 + 0], acc2);
            acc2 = fmaf(sv.y, w4c[4 * j4 + 1], acc2);
            acc2 = fmaf(sv.z, w4c[4 * j4 + 2], acc2);
            acc2 = fmaf(sv.w, w4c[4 * j4 + 3], acc2);
        }
        __builtin_amdgcn_wave_barrier();

        out[base] = x[base] + acc2;
    }
}

extern "C" void kernel_launch(void* const* d_in, const int* in_sizes, int n_in,
                              void* d_out, int out_size, void* d_ws, size_t ws_size,
                              hipStream_t stream) {
    const float* x      = (const float*)d_in[0];
    const float* coord  = (const float*)d_in[1];
    const float* rbf    = (const float*)d_in[2];
    const int*   ei     = (const int*)d_in[3];
    const float* W1 = (const float*)d_in[4];
    const float* b1 = (const float*)d_in[5];
    const float* W2 = (const float*)d_in[6];
    const float* b2 = (const float*)d_in[7];
    const float* W3 = (const float*)d_in[8];
    const float* b3 = (const float*)d_in[9];
    const float* W4 = (const float*)d_in[10];
    const float* b4 = (const float*)d_in[11];
    float* out = (float*)d_out;

    const long long E = in_sizes[3] / 2;
    const int nn = in_sizes[0] / EMBED;

    const size_t aggBytes = (size_t)nn * EMBED * sizeof(float);
    float* agg = (ws_size >= aggBytes) ? (float*)d_ws : out;

    hipMemsetAsync(agg, 0, aggBytes, stream);

    const long long eblocks = (E + EPB - 1) / EPB;
    edge_kernel<<<dim3((unsigned)eblocks), dim3(256), 0, stream>>>(
        coord, rbf, ei, W1, b1, W2, b2, agg, E);
    node_kernel<<<dim3(2048), dim3(256), 0, stream>>>(
        x, agg, W3, b3, W4, b4, out, nn);
}

// Round 5
// 477.227 us; speedup vs baseline: 1.5537x; 1.5537x over previous
//
#include <hip/hip_runtime.h>
#include <hip/hip_fp16.h>

typedef __attribute__((ext_vector_type(8))) short bf16x8;
typedef __attribute__((ext_vector_type(4))) float f32x4;

constexpr int EMBED = 64;
constexpr int RBF   = 16;
constexpr int EPB   = 256;   // edges per block (4 waves x 64)
constexpr int EPW   = 64;    // edges per wave

__device__ __forceinline__ short f2bf(float f) {
    unsigned u = __float_as_uint(f);
    unsigned r = (u + 0x7fffu + ((u >> 16) & 1u)) >> 16;   // RNE
    return (short)(r & 0xffffu);
}

__device__ __forceinline__ unsigned pk_f16(float lo, float hi) {
    __half2 h = __halves2half2(__float2half_rn(lo), __float2half_rn(hi));
    return *reinterpret_cast<unsigned*>(&h);
}

__device__ __forceinline__ void atom_pk_add_f16(__half* addr, unsigned data) {
    asm volatile("global_atomic_pk_add_f16 %0, %1, off"
                 :: "v"(addr), "v"(data) : "memory");
}

// Output-channel permutation for GEMM2: lane c (n=c) accumulator t holds
// channel ch(t,c) = (t&1) + 2c + 32*(t>>1)  ->  (acc2[0],acc2[1]) and
// (acc2[2],acc2[3]) are adjacent channel pairs -> lane-local packed atomics.
__device__ __forceinline__ int ch_map(int t, int c) {
    return (t & 1) + 2 * c + 32 * (t >> 1);
}

// ---------------------------------------------------------------------------
// Edge kernel, MFMA + packed-fp16 atomic scatter (USE_F16) or fp32 fallback.
// ---------------------------------------------------------------------------
template <bool USE_F16>
__global__ __launch_bounds__(256, 2) void edge_kernel(
    const float* __restrict__ coord,
    const float* __restrict__ rbf,
    const int* __restrict__ edge_index,
    const float* __restrict__ W1,
    const float* __restrict__ b1,
    const float* __restrict__ W2,
    const float* __restrict__ b2,
    void* __restrict__ aggv,
    long long E)
{
    __shared__ int lds_row[EPB];
    __shared__ __align__(16) short lds_s[4][4][16 * 64];  // [wave][mtile][16e x 64ch]

    const int tid  = threadIdx.x;
    const int lane = tid & 63;
    const int wave = tid >> 6;
    const int g = lane >> 4;     // 16-lane group 0..3
    const int c = lane & 15;
    const long long blk_e0 = (long long)blockIdx.x * EPB;

    {
        long long e = blk_e0 + tid;
        lds_row[tid] = (e < E) ? edge_index[e] : 0;
    }
    __builtin_amdgcn_wave_barrier();

    // ---- B fragments (VGPR-resident). B layout: n = c, k = g*8 + j ----
    bf16x8 b1f[4];
#pragma unroll
    for (int t = 0; t < 4; ++t) {
#pragma unroll
        for (int j = 0; j < 8; ++j) {
            const int k = g * 8 + j;
            const int n = t * 16 + c;
            b1f[t][j] = (k <= RBF) ? f2bf(W1[k * EMBED + n]) : (short)0;
        }
    }
    bf16x8 b2f[2][4];
#pragma unroll
    for (int kk = 0; kk < 2; ++kk)
#pragma unroll
        for (int t = 0; t < 4; ++t) {
            const int ch = ch_map(t, c);
#pragma unroll
            for (int j = 0; j < 8; ++j) {
                const int k = kk * 32 + g * 8 + j;
                b2f[kk][t][j] = f2bf(W2[k * EMBED + ch]);
            }
        }
    float b1v[4], b2v[4];
#pragma unroll
    for (int t = 0; t < 4; ++t) {
        b1v[t] = b1[t * 16 + c];
        b2v[t] = b2[ch_map(t, c)];
    }

    const long long wave_e0 = blk_e0 + (long long)wave * EPW;

    // ================= hoisted A1 builds (loads overlap) =================
    bf16x8 a1[4];
#pragma unroll
    for (int mt = 0; mt < 4; ++mt) {
        bf16x8 a = {};
        const long long e0 = wave_e0 + mt * 16;
        const int eloc0 = wave * EPW + mt * 16;
        const long long ea = e0 + c;
        const bool ev = (ea < E);
        if (g < 2) {
            if (ev) {
                const float4 p0 = *reinterpret_cast<const float4*>(rbf + ea * RBF + g * 8);
                const float4 p1 = *reinterpret_cast<const float4*>(rbf + ea * RBF + g * 8 + 4);
                a[0] = f2bf(p0.x); a[1] = f2bf(p0.y); a[2] = f2bf(p0.z); a[3] = f2bf(p0.w);
                a[4] = f2bf(p1.x); a[5] = f2bf(p1.y); a[6] = f2bf(p1.z); a[7] = f2bf(p1.w);
            }
        } else if (g == 2) {
            if (ev) {  // k=16 = angle, faithful to reference
                const int row = lds_row[eloc0 + c];
                const int col = edge_index[E + ea];
                const float vx = coord[row * 3 + 0] - coord[col * 3 + 0];
                const float vy = coord[row * 3 + 1] - coord[col * 3 + 1];
                const float vz = coord[row * 3 + 2] - coord[col * 3 + 2];
                const float sq = vx * vx + vy * vy + vz * vz;
                const float nrm = fmaxf(sqrtf(sq), 1e-12f);
                const float inv = 1.0f / nrm;
                const float ux = vx * inv, uy = vy * inv, uz = vz * inv;
                const float s2 = ux * ux + uy * uy + uz * uz;
                const float cosang = fminf(fmaxf(-s2, -1.0f), 1.0f);
                const float ang = acosf(cosang);
                a[0] = f2bf(ang);
            }
        }
        a1[mt] = a;
    }

    // ================= pass A: GEMM1 + SiLU + LDS (per-tile regions) =====
#pragma unroll
    for (int mt = 0; mt < 4; ++mt) {
        f32x4 acc1[4];
#pragma unroll
        for (int t = 0; t < 4; ++t) {
            f32x4 ci = {b1v[t], b1v[t], b1v[t], b1v[t]};
            acc1[t] = __builtin_amdgcn_mfma_f32_16x16x32_bf16(a1[mt], b1f[t], ci, 0, 0, 0);
        }
        char* const sl = reinterpret_cast<char*>(lds_s[wave][mt]);
#pragma unroll
        for (int t = 0; t < 4; ++t)
#pragma unroll
            for (int r = 0; r < 4; ++r) {
                const float x = acc1[t][r];
                const float s = x / (1.0f + __expf(-x));
                const int erow = g * 4 + r;
                const int byte = erow * 128 + ((t * 32 + 2 * c) ^ ((erow & 7) << 4));
                *reinterpret_cast<short*>(sl + byte) = f2bf(s);
            }
    }
    __builtin_amdgcn_wave_barrier();

    // ================= pass B: GEMM2 + atomics ===========================
#pragma unroll
    for (int mt = 0; mt < 4; ++mt) {
        const long long e0 = wave_e0 + mt * 16;
        const int eloc0 = wave * EPW + mt * 16;
        const char* const sl = reinterpret_cast<const char*>(lds_s[wave][mt]);

        bf16x8 a2[2];
#pragma unroll
        for (int kk = 0; kk < 2; ++kk) {
            const int byte = c * 128 + ((kk * 64 + g * 16) ^ ((c & 7) << 4));
            a2[kk] = *reinterpret_cast<const bf16x8*>(sl + byte);
        }

        f32x4 acc2[4];
#pragma unroll
        for (int t = 0; t < 4; ++t) {
            f32x4 ci = {b2v[t], b2v[t], b2v[t], b2v[t]};
            acc2[t] = __builtin_amdgcn_mfma_f32_16x16x32_bf16(a2[0], b2f[0][t], ci, 0, 0, 0);
            acc2[t] = __builtin_amdgcn_mfma_f32_16x16x32_bf16(a2[1], b2f[1][t], acc2[t], 0, 0, 0);
        }

        // lane holds edge g*4+r, channels ch_map(t,c)
#pragma unroll
        for (int r = 0; r < 4; ++r) {
            const long long eat = e0 + g * 4 + r;
            if (eat < E) {
                const long long rowoff = (long long)lds_row[eloc0 + g * 4 + r] * EMBED;
                if (USE_F16) {
                    __half* const dst = reinterpret_cast<__half*>(aggv) + rowoff;
                    atom_pk_add_f16(dst + 2 * c,      pk_f16(acc2[0][r], acc2[1][r]));
                    atom_pk_add_f16(dst + 32 + 2 * c, pk_f16(acc2[2][r], acc2[3][r]));
                } else {
                    float* const dst = reinterpret_cast<float*>(aggv) + rowoff;
                    atomicAdd(dst + 2 * c,      acc2[0][r]);
                    atomicAdd(dst + 2 * c + 1,  acc2[1][r]);
                    atomicAdd(dst + 32 + 2 * c, acc2[2][r]);
                    atomicAdd(dst + 33 + 2 * c, acc2[3][r]);
                }
            }
        }
    }
}

// ---------------------------------------------------------------------------
// Node kernel: out = x + W4 @ silu(W3 @ agg + b3) + b4 ; one wave per node.
// ---------------------------------------------------------------------------
template <bool USE_F16>
__global__ __launch_bounds__(256) void node_kernel(
    const float* __restrict__ x,
    const void* __restrict__ aggv,
    const float* __restrict__ W3,
    const float* __restrict__ b3,
    const float* __restrict__ W4,
    const float* __restrict__ b4,
    float* __restrict__ out,
    int nn)
{
    __shared__ __align__(16) float lds_s[4][EMBED];
    const int lane = threadIdx.x & 63;
    const int wave = threadIdx.x >> 6;

    float w3c[EMBED], w4c[EMBED];
#pragma unroll
    for (int j = 0; j < EMBED; ++j) w3c[j] = W3[j * EMBED + lane];
#pragma unroll
    for (int j = 0; j < EMBED; ++j) w4c[j] = W4[j * EMBED + lane];
    const float b3v = b3[lane];
    const float b4v = b4[lane];

    const float4* s4 = reinterpret_cast<const float4*>(lds_s[wave]);

    const int wid = blockIdx.x * 4 + wave;
    const int nw  = gridDim.x * 4;
    for (int n = wid; n < nn; n += nw) {
        const long long base = (long long)n * EMBED + lane;
        float a;
        if (USE_F16) {
            a = __half2float(reinterpret_cast<const __half*>(aggv)[base]);
        } else {
            a = reinterpret_cast<const float*>(aggv)[base];
        }

        lds_s[wave][lane] = a;
        __builtin_amdgcn_wave_barrier();

        float acc = b3v;
#pragma unroll
        for (int j4 = 0; j4 < EMBED / 4; ++j4) {
            const float4 sv = s4[j4];
            acc = fmaf(sv.x, w3c[4 * j4 + 0], acc);
            acc = fmaf(sv.y, w3c[4 * j4 + 1], acc);
            acc = fmaf(sv.z, w3c[4 * j4 + 2], acc);
            acc = fmaf(sv.w, w3c[4 * j4 + 3], acc);
        }
        const float s = acc / (1.0f + __expf(-acc));

        __builtin_amdgcn_wave_barrier();
        lds_s[wave][lane] = s;
        __builtin_amdgcn_wave_barrier();

        float acc2 = b4v;
#pragma unroll
        for (int j4 = 0; j4 < EMBED / 4; ++j4) {
            const float4 sv = s4[j4];
            acc2 = fmaf(sv.x, w4c[4 * j4 + 0], acc2);
            acc2 = fmaf(sv.y, w4c[4 * j4 + 1], acc2);
            acc2 = fmaf(sv.z, w4c[4 * j4 + 2], acc2);
            acc2 = fmaf(sv.w, w4c[4 * j4 + 3], acc2);
        }
        __builtin_amdgcn_wave_barrier();

        out[base] = x[base] + acc2;
    }
}

extern "C" void kernel_launch(void* const* d_in, const int* in_sizes, int n_in,
                              void* d_out, int out_size, void* d_ws, size_t ws_size,
                              hipStream_t stream) {
    const float* x      = (const float*)d_in[0];
    const float* coord  = (const float*)d_in[1];
    const float* rbf    = (const float*)d_in[2];
    const int*   ei     = (const int*)d_in[3];
    const float* W1 = (const float*)d_in[4];
    const float* b1 = (const float*)d_in[5];
    const float* W2 = (const float*)d_in[6];
    const float* b2 = (const float*)d_in[7];
    const float* W3 = (const float*)d_in[8];
    const float* b3 = (const float*)d_in[9];
    const float* W4 = (const float*)d_in[10];
    const float* b4 = (const float*)d_in[11];
    float* out = (float*)d_out;

    const long long E = in_sizes[3] / 2;
    const int nn = in_sizes[0] / EMBED;

    const size_t aggF16Bytes = (size_t)nn * EMBED * sizeof(__half);
    const long long eblocks = (E + EPB - 1) / EPB;

    if (ws_size >= aggF16Bytes) {
        // primary: packed-fp16 atomic aggregation in workspace
        hipMemsetAsync(d_ws, 0, aggF16Bytes, stream);
        edge_kernel<true><<<dim3((unsigned)eblocks), dim3(256), 0, stream>>>(
            coord, rbf, ei, W1, b1, W2, b2, d_ws, E);
        node_kernel<true><<<dim3(2048), dim3(256), 0, stream>>>(
            x, d_ws, W3, b3, W4, b4, out, nn);
    } else {
        // fallback: fp32 atomics into d_out, node MLP in place
        hipMemsetAsync(out, 0, (size_t)nn * EMBED * sizeof(float), stream);
        edge_kernel<false><<<dim3((unsigned)eblocks), dim3(256), 0, stream>>>(
            coord, rbf, ei, W1, b1, W2, b2, out, E);
        node_kernel<false><<<dim3(2048), dim3(256), 0, stream>>>(
            x, out, W3, b3, W4, b4, out, nn);
    }
}